// Round 4
// baseline (437.051 us; speedup 1.0000x reference)
//
#include <hip/hip_runtime.h>
#include <stdint.h>
#include <math.h>

// ---------------------------------------------------------------------------
// IID segmentation loss on MI355X.  Round 6 (= R5 resubmit; infra failure,
// no counters). Audit found no hang/fault path; only change is
// __launch_bounds__(640,3)->(640,2): LDS 151KB caps us at 1 block/CU anyway,
// so 3 waves/SIMD was a needless regalloc constraint.
// R5 theory: LDS-volume-bound at measured 12cyc/b128. K-split retile:
// 10 waves = 2 K-groups (xc 0-2 / 3-6) x 5 waves; each wave owns 20 tiles
// (w5<4: 4Mx5N shares bfrag; w5==4: 2Mx10N shares afrag). LDS ops/row
// 530->376 b128. Epilogue: kg1 dumps acc to LDS overlay, kg0 adds+stores.
// setprio around MFMA clusters; fused reduce_all; vectorized prep_b.
// ---------------------------------------------------------------------------

#define PADV 7
#define TS 15
#define KCLS 10
#define HH 224
#define WW 224
#define MD 160
#define NCELL (MD*MD)
#define NBLK 256
#define TY 14
#define BSTRIDE 232
#define BPH 240
#define PLANEE 2408          // elems per shift-plane (10*240 + 8 pad)
#define ABUFE (8*PLANEE)     // elems per A buffer (8 planes)
#define LDSA_BYTES (2*ABUFE*2)            // 77056
#define LDSB_BYTES (KCLS*16*BSTRIDE*2)    // 74240
#define LEPS 1e-16

typedef __attribute__((ext_vector_type(4))) float f32x4;
typedef __attribute__((ext_vector_type(8))) short bf16x8;

__device__ __forceinline__ unsigned short f2bf(float f) {
  union { float f; uint32_t u; } v; v.f = f;
  return (unsigned short)((v.u + 0x7FFFu + ((v.u >> 16) & 1u)) >> 16);
}

__device__ __forceinline__ uint32_t pack2bf(float a, float b) {
  return (uint32_t)f2bf(a) | ((uint32_t)f2bf(b) << 16);
}

__device__ __forceinline__ void glds16(const unsigned short* g, unsigned short* l) {
  __builtin_amdgcn_global_load_lds(
      (const __attribute__((address_space(1))) unsigned int*)g,
      (__attribute__((address_space(3))) unsigned int*)l, 16, 0, 0);
}

// Write the 8 shift-planes for one (class, 8-elem chunk) from 16 loaded f32.
__device__ __forceinline__ void plane_write(const f32x4 f[4], unsigned short* awr) {
  uint32_t w[8];
#pragma unroll
  for (int k = 0; k < 8; ++k)
    w[k] = pack2bf(f[k >> 1][(k & 1) * 2], f[k >> 1][(k & 1) * 2 + 1]);
#pragma unroll
  for (int c = 0; c < 8; ++c) {
    union { uint32_t u[4]; uint4 v; } o;
    if (c & 1) {
#pragma unroll
      for (int j = 0; j < 4; ++j) o.u[j] = w[j + (c + 1) / 2];
    } else {
#pragma unroll
      for (int j = 0; j < 4; ++j)
        o.u[j] = __builtin_amdgcn_alignbit(w[j + 1 + c / 2], w[j + c / 2], 16);
    }
    *(uint4*)(awr + c * PLANEE) = o.v;
  }
}

// Per-K-group compute: xc in [XB,XE), two (2Mx5N) sub-chunks per wave.
template<int XB, int XE>
__device__ __forceinline__ void compute_xcs(
    const unsigned short* __restrict__ paB, const unsigned short* __restrict__ lB,
    int slotB, bool shareB, int Mb0, int Nb0, int q8, f32x4 (&acc)[2][2][5]) {
#pragma unroll
  for (int xc = XB; xc < XE; ++xc) {
    const int qo = xc * 32 + q8;
    if (shareB) {
      bf16x8 bfrag[5];
#pragma unroll
      for (int ni = 0; ni < 5; ++ni)
        bfrag[ni] = *(const bf16x8*)(lB + ((Nb0 + ni) * 16 + slotB) * BSTRIDE + qo);
#pragma unroll
      for (int sub = 0; sub < 2; ++sub) {
        bf16x8 afrag[2];
#pragma unroll
        for (int mi = 0; mi < 2; ++mi)
          afrag[mi] = *(const bf16x8*)(paB + (Mb0 + 2 * sub + mi) * 240 + qo);
        __builtin_amdgcn_s_setprio(1);
#pragma unroll
        for (int mi = 0; mi < 2; ++mi)
#pragma unroll
          for (int ni = 0; ni < 5; ++ni)
            acc[sub][mi][ni] = __builtin_amdgcn_mfma_f32_16x16x32_bf16(
                afrag[mi], bfrag[ni], acc[sub][mi][ni], 0, 0, 0);
        __builtin_amdgcn_s_setprio(0);
      }
    } else {
      bf16x8 afrag[2];
#pragma unroll
      for (int mi = 0; mi < 2; ++mi)
        afrag[mi] = *(const bf16x8*)(paB + (Mb0 + mi) * 240 + qo);
#pragma unroll
      for (int sub = 0; sub < 2; ++sub) {
        bf16x8 bfrag[5];
#pragma unroll
        for (int ni = 0; ni < 5; ++ni)
          bfrag[ni] = *(const bf16x8*)(lB + ((5 * sub + ni) * 16 + slotB) * BSTRIDE + qo);
        __builtin_amdgcn_s_setprio(1);
#pragma unroll
        for (int mi = 0; mi < 2; ++mi)
#pragma unroll
          for (int ni = 0; ni < 5; ++ni)
            acc[sub][mi][ni] = __builtin_amdgcn_mfma_f32_16x16x32_bf16(
                afrag[mi], bfrag[ni], acc[sub][mi][ni], 0, 0, 0);
        __builtin_amdgcn_s_setprio(0);
      }
    }
  }
}

// Bpad[cls][yy][x]: cls=b*10+o, yy in [0,240) <-> row=yy-7, x in [0,232).
__global__ __launch_bounds__(256)
void prep_b(const float* __restrict__ xt, unsigned short* __restrict__ bp) {
  const int idx   = blockIdx.x * 256 + threadIdx.x;
  const int rowid = idx / 29;
  const int chunk = idx - rowid * 29;
  const int x0    = chunk * 8;
  const int yy    = rowid % BPH;
  const int cls   = rowid / BPH;
  const int row   = yy - PADV;
  union { unsigned short h[8]; uint4 v; } out;
  if (row >= 0 && row < HH && chunk < 28) {
    const float4* src = (const float4*)(xt + ((size_t)cls * HH + row) * WW + x0);
    const float4 f0 = src[0], f1 = src[1];
    out.h[0] = f2bf(f0.x); out.h[1] = f2bf(f0.y);
    out.h[2] = f2bf(f0.z); out.h[3] = f2bf(f0.w);
    out.h[4] = f2bf(f1.x); out.h[5] = f2bf(f1.y);
    out.h[6] = f2bf(f1.z); out.h[7] = f2bf(f1.w);
  } else {
    out.v = make_uint4(0u, 0u, 0u, 0u);
  }
  *(uint4*)(bp + (size_t)rowid * BSTRIDE + x0) = out.v;
}

__global__ __launch_bounds__(640, 2)
void corr_gemm(const float* __restrict__ xo, const unsigned short* __restrict__ bpad,
               float* __restrict__ partials) {
  __shared__ __align__(16) unsigned char smem[LDSA_BYTES + LDSB_BYTES];
  unsigned short* const ldsA8 = (unsigned short*)smem;
  unsigned short* const ldsB  = (unsigned short*)(smem + LDSA_BYTES);
  float* const scratch        = (float*)smem;   // epilogue overlay (102.4KB)

  const int tid  = threadIdx.x;
  const int bid0 = blockIdx.x;
  // XCD-bijective swizzle (256 = 8*32): 32 consecutive logical blocks per XCD.
  const int bid  = (bid0 & 7) * 32 + (bid0 >> 3);
  const int b    = bid >> 4;           // 16 batches
  const int y0   = (bid & 15) * TY;    // 16 groups of 14 rows

  const int lane = tid & 63;
  const int wv   = tid >> 6;           // 0..9
  const int kg   = (wv >= 5);          // K-group: 0 -> xc 0-2, 1 -> xc 3-6
  const int w5   = kg ? wv - 5 : wv;   // 0..4 within group
  const int quad = lane >> 4;
  const int l15  = lane & 15;
  const int q8   = quad * 8;

  const bool shareB = (w5 < 4);
  const int Mb0 = shareB ? (w5 >> 1) * 4 : 8;
  const int Nb0 = shareB ? (w5 & 1) * 5 : 0;

  f32x4 acc[2][2][5];
#pragma unroll
  for (int s2 = 0; s2 < 2; ++s2)
#pragma unroll
    for (int i = 0; i < 2; ++i)
#pragma unroll
      for (int j = 0; j < 5; ++j) acc[s2][i][j] = (f32x4){0.f, 0.f, 0.f, 0.f};

  const float* Ab = xo + (size_t)b * KCLS * HH * WW;
  const unsigned short* Bb = bpad + (size_t)b * KCLS * BPH * BSTRIDE;

  // A-row loader geometry: threads 0..299 (waves 0-4 = kgroup 0).
  const bool aw  = tid < 300;
  const int an   = aw ? tid / 30 : 0;
  const int atp  = aw ? tid - (tid / 30) * 30 : 0;
  const int axb  = atp * 8 - 8;
  bool gv[4];
#pragma unroll
  for (int g = 0; g < 4; ++g)
    gv[g] = aw && (axb + 4 * g >= 0) && (axb + 4 * g + 4 <= WW);
  unsigned short* const awr0 = ldsA8 + an * 240 + atp * 8;

  // prologue: async preload B rows y0-7..y0+7 (150 class-rows, 15/wave)
  for (int pr = wv; pr < 15 * KCLS; pr += 10) {
    const int r15  = pr / KCLS;
    const int o    = pr - r15 * KCLS;
    const int yy   = y0 + r15;
    const int slot = (y0 - PADV + r15) & 15;
    if (lane < 29)
      glds16(Bb + ((size_t)o * BPH + yy) * BSTRIDE + lane * 8,
             ldsB + (o * 16 + slot) * BSTRIDE);
  }

  // prologue: A row y0 -> planes in buf 0
  f32x4 f[4];
  {
    const float* src = Ab + ((size_t)an * HH + y0) * WW + axb;
#pragma unroll
    for (int g = 0; g < 4; ++g) {
      f[g] = (f32x4){0.f, 0.f, 0.f, 0.f};
      if (gv[g]) f[g] = *(const f32x4*)(src + 4 * g);
    }
  }
  if (aw) plane_write(f, awr0);
  __syncthreads();  // drains B prologue DMA + publishes A planes (buf 0)

  int cur = 0;
  for (int s = 0; s < TY; ++s) {
    const int y = y0 + s;
    const bool more = (s + 1 < TY);

    if (more) {
      if (kg == 1) {
        // async DMA: B row y+8 into dead slot (2 class-rows per kg1 wave)
        const int yy   = y + 8 + PADV;
        const int slot = (y + 8) & 15;
#pragma unroll
        for (int j = 0; j < 2; ++j) {
          const int ro = w5 * 2 + j;
          if (lane < 29)
            glds16(Bb + ((size_t)ro * BPH + yy) * BSTRIDE + lane * 8,
                   ldsB + (ro * 16 + slot) * BSTRIDE);
        }
      }
      // issue A row y+1 global loads early (kg0 loader threads)
      const float* src = Ab + ((size_t)an * HH + (y + 1)) * WW + axb;
#pragma unroll
      for (int g = 0; g < 4; ++g) {
        f[g] = (f32x4){0.f, 0.f, 0.f, 0.f};
        if (gv[g]) f[g] = *(const f32x4*)(src + 4 * g);
      }
    }

    const unsigned short* paB = ldsA8 + cur * ABUFE + (l15 & 7) * PLANEE + (l15 & 8);
    const int slotB = (y + PADV - l15) & 15;

    if (kg == 0)
      compute_xcs<0, 3>(paB, ldsB, slotB, shareB, Mb0, Nb0, q8, acc);
    else
      compute_xcs<3, 7>(paB, ldsB, slotB, shareB, Mb0, Nb0, q8, acc);

    if (more) {
      if (aw) plane_write(f, awr0 + (cur ^ 1) * ABUFE);
      __syncthreads();  // drains B DMA + publishes A planes (buf cur^1)
      cur ^= 1;
    }
  }

  // ---- epilogue: cross-K-group reduction via LDS overlay ----
  __syncthreads();  // last-row tile reads complete before overlay writes
  if (kg == 1) {
    float* dst = scratch + w5 * 5120 + lane * 4;
#pragma unroll
    for (int sub = 0; sub < 2; ++sub)
#pragma unroll
      for (int mi = 0; mi < 2; ++mi)
#pragma unroll
        for (int ni = 0; ni < 5; ++ni) {
          const int t = (sub * 2 + mi) * 5 + ni;
          *(f32x4*)(dst + t * 256) = acc[sub][mi][ni];
        }
  }
  __syncthreads();
  if (kg == 0) {
    const float* src = scratch + w5 * 5120 + lane * 4;
    float* outp = partials + (size_t)bid * NCELL;
#pragma unroll
    for (int sub = 0; sub < 2; ++sub)
#pragma unroll
      for (int mi = 0; mi < 2; ++mi)
#pragma unroll
        for (int ni = 0; ni < 5; ++ni) {
          const int t = (sub * 2 + mi) * 5 + ni;
          f32x4 o = *(const f32x4*)(src + t * 256);
          o += acc[sub][mi][ni];
          const int tm = shareB ? (Mb0 + 2 * sub + mi) : (8 + mi);
          const int to = shareB ? (Nb0 + ni) : (5 * sub + ni);
          const int mrow = tm * 16 + quad * 4;
          const int ncol = to * 16 + l15;
#pragma unroll
          for (int r = 0; r < 4; ++r)
            outp[(size_t)(mrow + r) * MD + ncol] = o[r];
        }
  }
}

// Fused stage1+final: sum 256 partial grids per cell, write Cmat + per-block mins.
__global__ __launch_bounds__(256)
void reduce_all(const float* __restrict__ partials, float* __restrict__ Cout,
                float* __restrict__ mins, float* __restrict__ dout) {
  const int c = blockIdx.x * 256 + threadIdx.x;
  if (blockIdx.x == 0 && threadIdx.x == 0) dout[0] = 0.f;
  const float* base = partials + c;
  double s0 = 0.0, s1 = 0.0, s2 = 0.0, s3 = 0.0;
  for (int p = 0; p < NBLK; p += 4) {
    s0 += (double)base[(size_t)(p + 0) * NCELL];
    s1 += (double)base[(size_t)(p + 1) * NCELL];
    s2 += (double)base[(size_t)(p + 2) * NCELL];
    s3 += (double)base[(size_t)(p + 3) * NCELL];
  }
  const float sf = (float)((s0 + s1) + (s2 + s3));
  Cout[c] = sf;
  const int m  = c / MD;
  const int nn = c - m * MD;
  const bool valid = ((m & 15) < TS) && ((nn & 15) < TS);
  __shared__ float red[256];
  red[threadIdx.x] = valid ? sf : 3.4e38f;
  __syncthreads();
  for (int st = 128; st > 0; st >>= 1) {
    if (threadIdx.x < st)
      red[threadIdx.x] = fminf(red[threadIdx.x], red[threadIdx.x + st]);
    __syncthreads();
  }
  if (threadIdx.x == 0) mins[blockIdx.x] = red[0];
}

__global__ __launch_bounds__(128)
void loss_kernel(const float* __restrict__ Cmat, const float* __restrict__ mins,
                 float* __restrict__ dout) {
  const int s   = blockIdx.x;
  const int dy  = s / TS;
  const int dx  = s - dy * TS;
  const int tid = threadIdx.x;
  __shared__ float fm[128];
  __shared__ double q[100];
  __shared__ double sym[100];
  __shared__ double pi[10], pj[10];
  __shared__ double red[128];

  fm[tid] = (tid < 100) ? mins[tid] : 3.4e38f;
  __syncthreads();
  for (int st = 64; st > 0; st >>= 1) {
    if (tid < st) fm[tid] = fminf(fm[tid], fm[tid + st]);
    __syncthreads();
  }
  const double minv = (double)fm[0];
  __syncthreads();

  if (tid < 100) {
    const int n = tid / 10, o = tid - (tid / 10) * 10;
    const double v = (double)Cmat[(size_t)(n * 16 + dx) * MD + (o * 16 + dy)];
    q[tid] = v - minv + LEPS;
  }
  __syncthreads();
  red[tid] = (tid < 100) ? q[tid] : 0.0;
  __syncthreads();
  for (int st = 64; st > 0; st >>= 1) {
    if (tid < st) red[tid] += red[tid + st];
    __syncthreads();
  }
  const double Z = red[0];
  __syncthreads();
  if (tid < 100) {
    const int n = tid / 10, o = tid - (tid / 10) * 10;
    sym[tid] = (q[n * 10 + o] + q[o * 10 + n]) * 0.5 / Z;
  }
  __syncthreads();
  if (tid < 10) {
    double a = 0.0, bsum = 0.0;
    for (int n2 = 0; n2 < 10; ++n2) {
      a    += sym[n2 * 10 + tid];
      bsum += sym[tid * 10 + n2];
    }
    pi[tid] = a;
    pj[tid] = bsum;
  }
  __syncthreads();
  double term = 0.0;
  if (tid < 100) {
    const int n = tid / 10, o = tid - (tid / 10) * 10;
    const double sp = sym[tid];
    term = -sp * (log(sp + LEPS) - log(pi[o] + LEPS) - log(pj[n] + LEPS));
  }
  red[tid] = term;
  __syncthreads();
  for (int st = 64; st > 0; st >>= 1) {
    if (tid < st) red[tid] += red[tid + st];
    __syncthreads();
  }
  if (tid == 0) atomicAdd(dout, (float)(red[0] / (double)(TS * TS)));
}

extern "C" void kernel_launch(void* const* d_in, const int* in_sizes, int n_in,
                              void* d_out, int out_size, void* d_ws, size_t ws_size,
                              hipStream_t stream) {
  const float* xo = (const float*)d_in[0];
  const float* xt = (const float*)d_in[1];
  float* ws       = (float*)d_ws;

  float* partials = ws;
  float* Cmat     = partials + (size_t)NBLK * NCELL;
  float* mins     = Cmat + NCELL;
  unsigned short* bpad = (unsigned short*)(mins + 128);
  float* out      = (float*)d_out;

  hipLaunchKernelGGL(prep_b,      dim3(4350), dim3(256), 0, stream, xt, bpad);
  hipLaunchKernelGGL(corr_gemm,   dim3(NBLK), dim3(640), 0, stream, xo, bpad, partials);
  hipLaunchKernelGGL(reduce_all,  dim3(100),  dim3(256), 0, stream, partials, Cmat, mins, out);
  hipLaunchKernelGGL(loss_kernel, dim3(225),  dim3(128), 0, stream, Cmat, mins, out);
}

// Round 5
// 148.677 us; speedup vs baseline: 2.9396x; 2.9396x over previous
//
#include <hip/hip_runtime.h>
#include <stdint.h>
#include <math.h>

// ---------------------------------------------------------------------------
// IID segmentation loss on MI355X.  Round 7.
// R6 post-mortem: K-split doubled acc (80 regs) + fully-unrolled xc loops ->
// accumulator spilled to scratch (WRITE_SIZE 864MB, 5.3KB/thread), corr 369us.
// R7: corr_gemm reverted byte-identical to R4 (known-good 56.5us, VGPR 68).
// Tail attack (tail was ~94us vs corr 57us): fused reduce_all kept from R6
// but re-parallelized 100->400 blocks (each thread sums 64 of 256 grids;
// old version was latency-bound at 400 waves total), vectorized prep_b,
// loss_kernel takes 400 partial mins. One fewer launch, no stage2 trip.
// ---------------------------------------------------------------------------

#define PADV 7
#define TS 15
#define KCLS 10
#define HH 224
#define WW 224
#define MD 160
#define NCELL (MD*MD)
#define NBLK 256
#define TY 14
#define BSTRIDE 232
#define BPH 240
#define PLANEE 2408          // elems per shift-plane (10*240 + 8 pad)
#define ABUFE (8*PLANEE)     // elems per A buffer (8 planes)
#define NRED 400             // reduce_all blocks (=mins entries)
#define LEPS 1e-16

typedef __attribute__((ext_vector_type(4))) float f32x4;
typedef __attribute__((ext_vector_type(8))) short bf16x8;

__device__ __forceinline__ unsigned short f2bf(float f) {
  union { float f; uint32_t u; } v; v.f = f;
  return (unsigned short)((v.u + 0x7FFFu + ((v.u >> 16) & 1u)) >> 16);
}

__device__ __forceinline__ uint32_t pack2bf(float a, float b) {
  return (uint32_t)f2bf(a) | ((uint32_t)f2bf(b) << 16);
}

__device__ __forceinline__ void glds16(const unsigned short* g, unsigned short* l) {
  __builtin_amdgcn_global_load_lds(
      (const __attribute__((address_space(1))) unsigned int*)g,
      (__attribute__((address_space(3))) unsigned int*)l, 16, 0, 0);
}

// Write the 8 shift-planes for one (class, 8-elem chunk) from 16 loaded f32.
__device__ __forceinline__ void plane_write(const f32x4 f[4], unsigned short* awr) {
  uint32_t w[8];
#pragma unroll
  for (int k = 0; k < 8; ++k)
    w[k] = pack2bf(f[k >> 1][(k & 1) * 2], f[k >> 1][(k & 1) * 2 + 1]);
#pragma unroll
  for (int c = 0; c < 8; ++c) {
    union { uint32_t u[4]; uint4 v; } o;
    if (c & 1) {
#pragma unroll
      for (int j = 0; j < 4; ++j) o.u[j] = w[j + (c + 1) / 2];
    } else {
#pragma unroll
      for (int j = 0; j < 4; ++j)
        o.u[j] = __builtin_amdgcn_alignbit(w[j + 1 + c / 2], w[j + c / 2], 16);
    }
    *(uint4*)(awr + c * PLANEE) = o.v;
  }
}

// Bpad[cls][yy][x]: cls=b*10+o, yy in [0,240) <-> row=yy-7, x in [0,232).
__global__ __launch_bounds__(256)
void prep_b(const float* __restrict__ xt, unsigned short* __restrict__ bp) {
  const int idx   = blockIdx.x * 256 + threadIdx.x;
  const int rowid = idx / 29;
  const int chunk = idx - rowid * 29;
  const int x0    = chunk * 8;
  const int yy    = rowid % BPH;
  const int cls   = rowid / BPH;
  const int row   = yy - PADV;
  union { unsigned short h[8]; uint4 v; } out;
  if (row >= 0 && row < HH && chunk < 28) {
    const float4* src = (const float4*)(xt + ((size_t)cls * HH + row) * WW + x0);
    const float4 f0 = src[0], f1 = src[1];
    out.h[0] = f2bf(f0.x); out.h[1] = f2bf(f0.y);
    out.h[2] = f2bf(f0.z); out.h[3] = f2bf(f0.w);
    out.h[4] = f2bf(f1.x); out.h[5] = f2bf(f1.y);
    out.h[6] = f2bf(f1.z); out.h[7] = f2bf(f1.w);
  } else {
    out.v = make_uint4(0u, 0u, 0u, 0u);
  }
  *(uint4*)(bp + (size_t)rowid * BSTRIDE + x0) = out.v;
}

// --- corr_gemm: byte-identical to R4 (known-good) ---
__global__ __launch_bounds__(640, 3)
void corr_gemm(const float* __restrict__ xo, const unsigned short* __restrict__ bpad,
               float* __restrict__ partials) {
  __shared__ __align__(16) unsigned short ldsA8[2 * ABUFE];
  __shared__ __align__(16) unsigned short ldsB[KCLS * 16 * BSTRIDE];

  const int tid  = threadIdx.x;
  const int bid0 = blockIdx.x;
  // XCD-bijective swizzle (256 = 8*32): 32 consecutive logical blocks per XCD.
  const int bid  = (bid0 & 7) * 32 + (bid0 >> 3);
  const int b    = bid >> 4;           // 16 batches
  const int y0   = (bid & 15) * TY;    // 16 groups of 14 rows

  const int lane = tid & 63;
  const int wv   = tid >> 6;
  const int wm   = wv >> 1;
  const int wn   = wv & 1;
  const int quad = lane >> 4;
  const int l15  = lane & 15;

  f32x4 acc[2][5];
#pragma unroll
  for (int i = 0; i < 2; ++i)
#pragma unroll
    for (int j = 0; j < 5; ++j) acc[i][j] = (f32x4){0.f, 0.f, 0.f, 0.f};

  const float* Ab = xo + (size_t)b * KCLS * HH * WW;
  const unsigned short* Bb = bpad + (size_t)b * KCLS * BPH * BSTRIDE;

  // A-row loader geometry: threads 0..299 -> (class an, chunk atp in [0,30)).
  const bool aw  = tid < 300;
  const int an   = aw ? tid / 30 : 0;
  const int atp  = aw ? tid - (tid / 30) * 30 : 0;
  const int axb  = atp * 8 - 8;        // global x of f[0].x
  bool gv[4];
#pragma unroll
  for (int g = 0; g < 4; ++g)
    gv[g] = aw && (axb + 4 * g >= 0) && (axb + 4 * g + 4 <= WW);
  unsigned short* const awr0 = ldsA8 + an * 240 + atp * 8;

  // prologue: async preload B rows y0-7..y0+7 (150 class-rows, 15/wave)
  for (int pr = wv; pr < 15 * KCLS; pr += 10) {
    const int r15  = pr / KCLS;
    const int o    = pr - r15 * KCLS;
    const int yy   = y0 + r15;                 // row = y0-7+r15
    const int slot = (y0 - PADV + r15) & 15;
    if (lane < 29)
      glds16(Bb + ((size_t)o * BPH + yy) * BSTRIDE + lane * 8,
             ldsB + (o * 16 + slot) * BSTRIDE);
  }

  // prologue: A row y0 -> planes in buf 0
  f32x4 f[4];
  {
    const float* src = Ab + ((size_t)an * HH + y0) * WW + axb;
#pragma unroll
    for (int g = 0; g < 4; ++g) {
      f[g] = (f32x4){0.f, 0.f, 0.f, 0.f};
      if (gv[g]) f[g] = *(const f32x4*)(src + 4 * g);
    }
  }
  if (aw) plane_write(f, awr0);
  __syncthreads();  // drains B prologue DMA + publishes A planes (buf 0)

  int cur = 0;
  for (int s = 0; s < TY; ++s) {
    const int y = y0 + s;
    const bool more = (s + 1 < TY);

    if (more) {
      // async DMA: B row y+8 into dead slot (one class-row per wave)
      const int yy   = y + 8 + PADV;
      const int slot = (y + 8) & 15;
      if (lane < 29)
        glds16(Bb + ((size_t)wv * BPH + yy) * BSTRIDE + lane * 8,
               ldsB + (wv * 16 + slot) * BSTRIDE);
      // issue A row y+1 global loads early (latency hides under MFMAs)
      const float* src = Ab + ((size_t)an * HH + (y + 1)) * WW + axb;
#pragma unroll
      for (int g = 0; g < 4; ++g) {
        f[g] = (f32x4){0.f, 0.f, 0.f, 0.f};
        if (gv[g]) f[g] = *(const f32x4*)(src + 4 * g);
      }
    }

    // per-lane bases: A plane read is a single aligned b128, conflict-free
    const unsigned short* paB = ldsA8 + cur * ABUFE + (l15 & 7) * PLANEE + (l15 & 8);
    const int slotB = (y + PADV - l15) & 15;

#pragma unroll 1
    for (int xc = 0; xc < 7; ++xc) {
      const int x0 = xc * 32;
      bf16x8 afrag[2], bfrag[5];
#pragma unroll
      for (int mi = 0; mi < 2; ++mi)
        afrag[mi] = *(const bf16x8*)(paB + (wm * 2 + mi) * 240 + x0 + quad * 8);
#pragma unroll
      for (int ni = 0; ni < 5; ++ni) {
        const int to = wn * 5 + ni;
        bfrag[ni] = *(const bf16x8*)(ldsB + (to * 16 + slotB) * BSTRIDE + x0 + quad * 8);
      }
#pragma unroll
      for (int mi = 0; mi < 2; ++mi)
#pragma unroll
        for (int ni = 0; ni < 5; ++ni)
          acc[mi][ni] = __builtin_amdgcn_mfma_f32_16x16x32_bf16(
              afrag[mi], bfrag[ni], acc[mi][ni], 0, 0, 0);
    }

    if (more) {
      if (aw) plane_write(f, awr0 + (cur ^ 1) * ABUFE);
      __syncthreads();  // drains B DMA + publishes A planes (buf cur^1)
      cur ^= 1;
    }
  }

  float* outp = partials + (size_t)bid * NCELL;
#pragma unroll
  for (int mi = 0; mi < 2; ++mi)
#pragma unroll
    for (int ni = 0; ni < 5; ++ni) {
      const int mrow = (wm * 2 + mi) * 16 + quad * 4;
      const int ncol = (wn * 5 + ni) * 16 + l15;
#pragma unroll
      for (int r = 0; r < 4; ++r)
        outp[(size_t)(mrow + r) * MD + ncol] = acc[mi][ni][r];
    }
}

// Fused reduce: 400 blocks. Block covers 64 cells; thread (cl,g) sums grids
// [g*64,(g+1)*64) for cell c = bid*64+cl; LDS-combine 4 groups; per-block min.
__global__ __launch_bounds__(256)
void reduce_all(const float* __restrict__ partials, float* __restrict__ Cout,
                float* __restrict__ mins, float* __restrict__ dout) {
  const int tid = threadIdx.x;
  const int cl  = tid & 63;
  const int g   = tid >> 6;
  const int c   = blockIdx.x * 64 + cl;
  if (blockIdx.x == 0 && tid == 0) dout[0] = 0.f;

  const float* base = partials + (size_t)g * 64 * NCELL + c;
  double s0 = 0.0, s1 = 0.0, s2 = 0.0, s3 = 0.0;
  for (int p = 0; p < 64; p += 4) {
    s0 += (double)base[(size_t)(p + 0) * NCELL];
    s1 += (double)base[(size_t)(p + 1) * NCELL];
    s2 += (double)base[(size_t)(p + 2) * NCELL];
    s3 += (double)base[(size_t)(p + 3) * NCELL];
  }
  __shared__ double redd[256];
  redd[tid] = (s0 + s1) + (s2 + s3);
  __syncthreads();

  __shared__ float redm[64];
  if (tid < 64) {
    const double tot = redd[tid] + redd[tid + 64] + redd[tid + 128] + redd[tid + 192];
    const float sf = (float)tot;
    Cout[c] = sf;
    const int m  = c / MD;
    const int nn = c - m * MD;
    const bool valid = ((m & 15) < TS) && ((nn & 15) < TS);
    redm[tid] = valid ? sf : 3.4e38f;
  }
  __syncthreads();
  for (int st = 32; st > 0; st >>= 1) {
    if (tid < st) redm[tid] = fminf(redm[tid], redm[tid + st]);
    __syncthreads();
  }
  if (tid == 0) mins[blockIdx.x] = redm[0];
}

__global__ __launch_bounds__(128)
void loss_kernel(const float* __restrict__ Cmat, const float* __restrict__ mins,
                 float* __restrict__ dout) {
  const int s   = blockIdx.x;
  const int dy  = s / TS;
  const int dx  = s - dy * TS;
  const int tid = threadIdx.x;
  __shared__ float fm[128];
  __shared__ double q[100];
  __shared__ double sym[100];
  __shared__ double pi[10], pj[10];
  __shared__ double red[128];

  {
    float v = 3.4e38f;
    for (int i = tid; i < NRED; i += 128) v = fminf(v, mins[i]);
    fm[tid] = v;
  }
  __syncthreads();
  for (int st = 64; st > 0; st >>= 1) {
    if (tid < st) fm[tid] = fminf(fm[tid], fm[tid + st]);
    __syncthreads();
  }
  const double minv = (double)fm[0];
  __syncthreads();

  if (tid < 100) {
    const int n = tid / 10, o = tid - (tid / 10) * 10;
    const double v = (double)Cmat[(size_t)(n * 16 + dx) * MD + (o * 16 + dy)];
    q[tid] = v - minv + LEPS;
  }
  __syncthreads();
  red[tid] = (tid < 100) ? q[tid] : 0.0;
  __syncthreads();
  for (int st = 64; st > 0; st >>= 1) {
    if (tid < st) red[tid] += red[tid + st];
    __syncthreads();
  }
  const double Z = red[0];
  __syncthreads();
  if (tid < 100) {
    const int n = tid / 10, o = tid - (tid / 10) * 10;
    sym[tid] = (q[n * 10 + o] + q[o * 10 + n]) * 0.5 / Z;
  }
  __syncthreads();
  if (tid < 10) {
    double a = 0.0, bsum = 0.0;
    for (int n2 = 0; n2 < 10; ++n2) {
      a    += sym[n2 * 10 + tid];
      bsum += sym[tid * 10 + n2];
    }
    pi[tid] = a;
    pj[tid] = bsum;
  }
  __syncthreads();
  double term = 0.0;
  if (tid < 100) {
    const int n = tid / 10, o = tid - (tid / 10) * 10;
    const double sp = sym[tid];
    term = -sp * (log(sp + LEPS) - log(pi[o] + LEPS) - log(pj[n] + LEPS));
  }
  red[tid] = term;
  __syncthreads();
  for (int st = 64; st > 0; st >>= 1) {
    if (tid < st) red[tid] += red[tid + st];
    __syncthreads();
  }
  if (tid == 0) atomicAdd(dout, (float)(red[0] / (double)(TS * TS)));
}

extern "C" void kernel_launch(void* const* d_in, const int* in_sizes, int n_in,
                              void* d_out, int out_size, void* d_ws, size_t ws_size,
                              hipStream_t stream) {
  const float* xo = (const float*)d_in[0];
  const float* xt = (const float*)d_in[1];
  float* ws       = (float*)d_ws;

  float* partials = ws;
  float* Cmat     = partials + (size_t)NBLK * NCELL;
  float* mins     = Cmat + NCELL;
  unsigned short* bpad = (unsigned short*)(mins + 512);
  float* out      = (float*)d_out;

  hipLaunchKernelGGL(prep_b,      dim3(4350), dim3(256), 0, stream, xt, bpad);
  hipLaunchKernelGGL(corr_gemm,   dim3(NBLK), dim3(640), 0, stream, xo, bpad, partials);
  hipLaunchKernelGGL(reduce_all,  dim3(NRED), dim3(256), 0, stream, partials, Cmat, mins, out);
  hipLaunchKernelGGL(loss_kernel, dim3(225),  dim3(128), 0, stream, Cmat, mins, out);
}